// Round 6
// baseline (2347.272 us; speedup 1.0000x reference)
//
#include <hip/hip_runtime.h>

// VQ-VAE VectorQuantizer forward, fp32, MI355X.
// B=64, C=D=64, H=W=32 -> N=65536 pixels, K=1024 codes.
// Outputs (flat concat): [0] loss, [1..4194305) quantized BCHW, [4194305..) indices (as float)
//
// R6: e-broadcast moved off the scalar pipe onto LDS.
// R5 lesson: s_load streaming of e is LATENCY-serialized (SGPRs can only stage
// ~100 dwords -> ~8 batch-waits of ~200cyc per 8-code group); halving traffic
// didn't help and VALUBusy fell to 44%. Now each wave double-buffers its 8-code
// group (2KB) in LDS: coalesced per-lane float4 loads (vector L2 path) ->
// ds_write_b128, T14 async-split (issue load g+2 before compute g, LDS-write
// after) so L2 latency hides under ~2500cyc of FMAs. e consumed via
// uniform-address ds_read_b128 broadcasts (conflict-free, 1 per 8 FMAs).
// Per-code arithmetic BIT-IDENTICAL to R0-R5 (passed, absmax 3.8e-6):
// pairwise-8 x_sq (fp-contract off), sequential d-ascending fp32 FMA dot,
// dist = (x_sq - 2*dot) + e_sq, strict-< ascending-k argmin, ascending-chunk merge.

#define KCODES 1024
#define DDIM   64
#define NPIX   65536        // B*H*W
#define QELEMS 4194304      // B*C*H*W
#define IDX_OFF (1 + QELEMS)
#define NWAVE  8            // waves per block = K chunks
#define CHUNK  (KCODES / NWAVE)   // 128 codes per wave
#define PXB    128          // pixels per block (2 per lane)
#define NGROUP (CHUNK / 8)  // 16 8-code groups per wave

// ---------------- e_sq precompute: replicate np.sum(e*e, axis=1) pairwise-8 ----------------
__global__ void __launch_bounds__(256) esq_kernel(const float* __restrict__ e,
                                                  float* __restrict__ esq) {
    int k = blockIdx.x * 256 + threadIdx.x;
    if (k >= KCODES) return;
    {
#pragma clang fp contract(off)
        const float* row = e + k * DDIM;
        float r[8];
#pragma unroll
        for (int j = 0; j < 8; ++j) r[j] = row[j] * row[j];
#pragma unroll
        for (int i = 1; i < 8; ++i) {
#pragma unroll
            for (int j = 0; j < 8; ++j) {
                float v = row[i * 8 + j];
                r[j] += v * v;
            }
        }
        esq[k] = ((r[0] + r[1]) + (r[2] + r[3])) + ((r[4] + r[5]) + (r[6] + r[7]));
    }
}

// x_sq helper: EXACT replication of numpy pairwise-8 (no fp contraction)
__device__ __forceinline__ float xsq_pairwise8(const float* xr) {
#pragma clang fp contract(off)
    float r[8];
#pragma unroll
    for (int j = 0; j < 8; ++j) r[j] = xr[j] * xr[j];
#pragma unroll
    for (int ii = 1; ii < 8; ++ii) {
#pragma unroll
        for (int j = 0; j < 8; ++j) {
            float v = xr[ii * 8 + j];
            r[j] += v * v;
        }
    }
    return ((r[0] + r[1]) + (r[2] + r[3])) + ((r[4] + r[5]) + (r[6] + r[7]));
}

// ---------------- main distance + argmin kernel (K-split, 2 px/lane, LDS e) ----------------
// Block = 512 threads = 8 waves. Wave w handles codes [w*128, w*128+128) for the
// block's 128 pixels: lane l owns pixels blk*128+l and blk*128+l+64.
__global__ void __launch_bounds__(512, 2) argmin_kernel(const float* __restrict__ x,
                                                        const float* __restrict__ e,
                                                        const float* __restrict__ esq,
                                                        int* __restrict__ idx_out,
                                                        float* __restrict__ out) {
    // per-wave double-buffered e staging: 8 codes x 64 floats = 2KB per buffer
    __shared__ float se[NWAVE][2][512];
    __shared__ float sbest[NWAVE][PXB];
    __shared__ int   sidx[NWAVE][PXB];

    const int w = __builtin_amdgcn_readfirstlane(threadIdx.x >> 6);
    const int l = threadIdx.x & 63;
    const int i0 = blockIdx.x * PXB + l;     // first pixel
    const int b = i0 >> 10;                  // 128-aligned block => same b for both px
    const int p0 = i0 & 1023;

    // x[b][d][p], d-stride = 1024 floats; lanes -> consecutive p (coalesced)
    const float* xb = x + (size_t)b * 65536 + p0;
    float xr0[DDIM], xr1[DDIM];
#pragma unroll
    for (int d = 0; d < DDIM; ++d) xr0[d] = xb[(size_t)d * 1024];
#pragma unroll
    for (int d = 0; d < DDIM; ++d) xr1[d] = xb[(size_t)d * 1024 + 64];
    // keep-alive anchors: opaque asm defs prevent rematerialization/reload
#pragma unroll
    for (int d = 0; d < DDIM; ++d) { asm volatile("" : "+v"(xr0[d])); asm volatile("" : "+v"(xr1[d])); }

    const float xsq0 = xsq_pairwise8(xr0);
    const float xsq1 = xsq_pairwise8(xr1);

    const int kbeg = w * CHUNK;              // uniform (SGPR)

    // staging: lane l covers bytes [16*l, 16*l+16) and [1024+16*l, ...) of the
    // 2KB group (8 codes x 256B, row-major) -> coalesced float4 loads.
    float4 st0, st1;
    auto LD = [&](int g) {
        const float* gp = e + (size_t)(kbeg + g * 8) * DDIM;
        st0 = *(const float4*)(gp + 4 * l);
        st1 = *(const float4*)(gp + 256 + 4 * l);
    };
    auto ST = [&](int parity) {
        *(float4*)&se[w][parity][4 * l] = st0;
        *(float4*)&se[w][parity][256 + 4 * l] = st1;
    };

    LD(0); ST(0);       // group 0 staged
    LD(1);              // group 1 in registers (written after compute(0))

    float best0 = 3.4e38f, best1 = 3.4e38f;
    int bidx0 = 0, bidx1 = 0;

#pragma unroll 1
    for (int g = 0; g < NGROUP; ++g) {
        const int k = kbeg + g * 8;
        const float* eb = &se[w][g & 1][0];

        float a0 = 0.f, a1 = 0.f, a2 = 0.f, a3 = 0.f, a4 = 0.f, a5 = 0.f, a6 = 0.f, a7 = 0.f;
        float c0 = 0.f, c1 = 0.f, c2 = 0.f, c3 = 0.f, c4 = 0.f, c5 = 0.f, c6 = 0.f, c7 = 0.f;
        // d-quads: uniform-address ds_read_b128 broadcasts, 8 codes per quad.
        // Chain order stays exactly d-ascending per code (d = q*4 + j).
#pragma unroll
        for (int q = 0; q < 16; ++q) {
            const float4 e0 = *(const float4*)&eb[0 * 64 + 4 * q];
            const float4 e1 = *(const float4*)&eb[1 * 64 + 4 * q];
            const float4 e2 = *(const float4*)&eb[2 * 64 + 4 * q];
            const float4 e3 = *(const float4*)&eb[3 * 64 + 4 * q];
            const float4 e4 = *(const float4*)&eb[4 * 64 + 4 * q];
            const float4 e5 = *(const float4*)&eb[5 * 64 + 4 * q];
            const float4 e6 = *(const float4*)&eb[6 * 64 + 4 * q];
            const float4 e7 = *(const float4*)&eb[7 * 64 + 4 * q];
            const float x00 = xr0[4 * q + 0], x01 = xr0[4 * q + 1], x02 = xr0[4 * q + 2], x03 = xr0[4 * q + 3];
            const float x10 = xr1[4 * q + 0], x11 = xr1[4 * q + 1], x12 = xr1[4 * q + 2], x13 = xr1[4 * q + 3];
            a0 = __builtin_fmaf(x00, e0.x, a0); a0 = __builtin_fmaf(x01, e0.y, a0); a0 = __builtin_fmaf(x02, e0.z, a0); a0 = __builtin_fmaf(x03, e0.w, a0);
            a1 = __builtin_fmaf(x00, e1.x, a1); a1 = __builtin_fmaf(x01, e1.y, a1); a1 = __builtin_fmaf(x02, e1.z, a1); a1 = __builtin_fmaf(x03, e1.w, a1);
            a2 = __builtin_fmaf(x00, e2.x, a2); a2 = __builtin_fmaf(x01, e2.y, a2); a2 = __builtin_fmaf(x02, e2.z, a2); a2 = __builtin_fmaf(x03, e2.w, a2);
            a3 = __builtin_fmaf(x00, e3.x, a3); a3 = __builtin_fmaf(x01, e3.y, a3); a3 = __builtin_fmaf(x02, e3.z, a3); a3 = __builtin_fmaf(x03, e3.w, a3);
            a4 = __builtin_fmaf(x00, e4.x, a4); a4 = __builtin_fmaf(x01, e4.y, a4); a4 = __builtin_fmaf(x02, e4.z, a4); a4 = __builtin_fmaf(x03, e4.w, a4);
            a5 = __builtin_fmaf(x00, e5.x, a5); a5 = __builtin_fmaf(x01, e5.y, a5); a5 = __builtin_fmaf(x02, e5.z, a5); a5 = __builtin_fmaf(x03, e5.w, a5);
            a6 = __builtin_fmaf(x00, e6.x, a6); a6 = __builtin_fmaf(x01, e6.y, a6); a6 = __builtin_fmaf(x02, e6.z, a6); a6 = __builtin_fmaf(x03, e6.w, a6);
            a7 = __builtin_fmaf(x00, e7.x, a7); a7 = __builtin_fmaf(x01, e7.y, a7); a7 = __builtin_fmaf(x02, e7.z, a7); a7 = __builtin_fmaf(x03, e7.w, a7);
            c0 = __builtin_fmaf(x10, e0.x, c0); c0 = __builtin_fmaf(x11, e0.y, c0); c0 = __builtin_fmaf(x12, e0.z, c0); c0 = __builtin_fmaf(x13, e0.w, c0);
            c1 = __builtin_fmaf(x10, e1.x, c1); c1 = __builtin_fmaf(x11, e1.y, c1); c1 = __builtin_fmaf(x12, e1.z, c1); c1 = __builtin_fmaf(x13, e1.w, c1);
            c2 = __builtin_fmaf(x10, e2.x, c2); c2 = __builtin_fmaf(x11, e2.y, c2); c2 = __builtin_fmaf(x12, e2.z, c2); c2 = __builtin_fmaf(x13, e2.w, c2);
            c3 = __builtin_fmaf(x10, e3.x, c3); c3 = __builtin_fmaf(x11, e3.y, c3); c3 = __builtin_fmaf(x12, e3.z, c3); c3 = __builtin_fmaf(x13, e3.w, c3);
            c4 = __builtin_fmaf(x10, e4.x, c4); c4 = __builtin_fmaf(x11, e4.y, c4); c4 = __builtin_fmaf(x12, e4.z, c4); c4 = __builtin_fmaf(x13, e4.w, c4);
            c5 = __builtin_fmaf(x10, e5.x, c5); c5 = __builtin_fmaf(x11, e5.y, c5); c5 = __builtin_fmaf(x12, e5.z, c5); c5 = __builtin_fmaf(x13, e5.w, c5);
            c6 = __builtin_fmaf(x10, e6.x, c6); c6 = __builtin_fmaf(x11, e6.y, c6); c6 = __builtin_fmaf(x12, e6.z, c6); c6 = __builtin_fmaf(x13, e6.w, c6);
            c7 = __builtin_fmaf(x10, e7.x, c7); c7 = __builtin_fmaf(x11, e7.y, c7); c7 = __builtin_fmaf(x12, e7.z, c7); c7 = __builtin_fmaf(x13, e7.w, c7);
        }

        // dist = (x_sq - 2*dot) + e_sq   (same association as np; /64 exact-monotone, skipped)
        const float q0 = esq[k + 0], q1 = esq[k + 1], q2 = esq[k + 2], q3 = esq[k + 3];
        const float q4 = esq[k + 4], q5 = esq[k + 5], q6 = esq[k + 6], q7 = esq[k + 7];
        float s0 = (xsq0 - 2.0f * a0) + q0;
        float s1 = (xsq0 - 2.0f * a1) + q1;
        float s2 = (xsq0 - 2.0f * a2) + q2;
        float s3 = (xsq0 - 2.0f * a3) + q3;
        float s4 = (xsq0 - 2.0f * a4) + q4;
        float s5 = (xsq0 - 2.0f * a5) + q5;
        float s6 = (xsq0 - 2.0f * a6) + q6;
        float s7 = (xsq0 - 2.0f * a7) + q7;
        float t0 = (xsq1 - 2.0f * c0) + q0;
        float t1 = (xsq1 - 2.0f * c1) + q1;
        float t2 = (xsq1 - 2.0f * c2) + q2;
        float t3 = (xsq1 - 2.0f * c3) + q3;
        float t4 = (xsq1 - 2.0f * c4) + q4;
        float t5 = (xsq1 - 2.0f * c5) + q5;
        float t6 = (xsq1 - 2.0f * c6) + q6;
        float t7 = (xsq1 - 2.0f * c7) + q7;
        // strict < , ascending k => first-occurrence min within chunk
        if (s0 < best0) { best0 = s0; bidx0 = k + 0; }
        if (s1 < best0) { best0 = s1; bidx0 = k + 1; }
        if (s2 < best0) { best0 = s2; bidx0 = k + 2; }
        if (s3 < best0) { best0 = s3; bidx0 = k + 3; }
        if (s4 < best0) { best0 = s4; bidx0 = k + 4; }
        if (s5 < best0) { best0 = s5; bidx0 = k + 5; }
        if (s6 < best0) { best0 = s6; bidx0 = k + 6; }
        if (s7 < best0) { best0 = s7; bidx0 = k + 7; }
        if (t0 < best1) { best1 = t0; bidx1 = k + 0; }
        if (t1 < best1) { best1 = t1; bidx1 = k + 1; }
        if (t2 < best1) { best1 = t2; bidx1 = k + 2; }
        if (t3 < best1) { best1 = t3; bidx1 = k + 3; }
        if (t4 < best1) { best1 = t4; bidx1 = k + 4; }
        if (t5 < best1) { best1 = t5; bidx1 = k + 5; }
        if (t6 < best1) { best1 = t6; bidx1 = k + 6; }
        if (t7 < best1) { best1 = t7; bidx1 = k + 7; }

        // T14 async-split tail: LDS-write the prefetched group (vmcnt wait lands
        // here, after ~2500cyc of compute), then issue the next global load.
        if (g + 1 < NGROUP) {
            ST((g + 1) & 1);
            if (g + 2 < NGROUP) LD(g + 2);
        }
    }

    // merge the 8 chunk results: ascending chunk + strict '<' == global first-min
    sbest[w][l] = best0;        sbest[w][l + 64] = best1;
    sidx[w][l] = bidx0;         sidx[w][l + 64] = bidx1;
    __syncthreads();
    if (threadIdx.x < PXB) {
        const int t = threadIdx.x;
        float bb = sbest[0][t];
        int bi = sidx[0][t];
#pragma unroll
        for (int c = 1; c < NWAVE; ++c) {
            float v = sbest[c][t];
            if (v < bb) { bb = v; bi = sidx[c][t]; }
        }
        const int gi = blockIdx.x * PXB + t;
        idx_out[gi] = bi;
        out[IDX_OFF + gi] = (float)bi;   // harness reads d_out as float32
    }
}

// ---------------- gather + transpose + per-block loss partials ----------------
// block = one (b,d) plane of 1024 pixels; coalesced read/write.
__global__ void __launch_bounds__(256) gather_kernel(const float* __restrict__ x,
                                                     const float* __restrict__ e,
                                                     const int* __restrict__ idx,
                                                     float* __restrict__ out,
                                                     float* __restrict__ partial) {
    const int bd = blockIdx.x;          // = b*64 + d
    const int b = bd >> 6;
    const int d = bd & 63;
    const size_t base = (size_t)bd * 1024;
    const int* idxb = idx + b * 1024;

    float acc = 0.f;
#pragma unroll
    for (int j = 0; j < 4; ++j) {
        int p = threadIdx.x + j * 256;
        int k = idxb[p];
        float ev = e[k * 64 + d];
        float xv = x[base + p];
        out[1 + base + p] = ev;         // quantized (straight-through == codebook value)
        float df = ev - xv;
        acc = __builtin_fmaf(df, df, acc);
    }
    __shared__ float sm[256];
    sm[threadIdx.x] = acc;
    __syncthreads();
    for (int s = 128; s > 0; s >>= 1) {
        if (threadIdx.x < s) sm[threadIdx.x] += sm[threadIdx.x + s];
        __syncthreads();
    }
    if (threadIdx.x == 0) partial[bd] = sm[0];
}

// ---------------- deterministic loss finalize ----------------
__global__ void __launch_bounds__(256) loss_kernel(const float* __restrict__ partial,
                                                   float* __restrict__ out) {
    float acc = 0.f;
    for (int i = threadIdx.x; i < 4096; i += 256) acc += partial[i];
    __shared__ float sm[256];
    sm[threadIdx.x] = acc;
    __syncthreads();
    for (int s = 128; s > 0; s >>= 1) {
        if (threadIdx.x < s) sm[threadIdx.x] += sm[threadIdx.x + s];
        __syncthreads();
    }
    // loss = q_latent + 0.25*e_latent = 1.25 * mean(diff^2)
    if (threadIdx.x == 0) out[0] = sm[0] * (1.25f / 4194304.f);
}

extern "C" void kernel_launch(void* const* d_in, const int* in_sizes, int n_in,
                              void* d_out, int out_size, void* d_ws, size_t ws_size,
                              hipStream_t stream) {
    const float* x = (const float*)d_in[0];   // [64,64,32,32]
    const float* e = (const float*)d_in[1];   // [1024,64]
    float* out = (float*)d_out;

    // ws: [0,4KB) e_sq | [4KB, 4KB+256KB) idx int32 | then 16KB partials
    float* esq = (float*)d_ws;
    int* idx = (int*)((char*)d_ws + 4096);
    float* partial = (float*)((char*)d_ws + 4096 + NPIX * 4);

    esq_kernel<<<4, 256, 0, stream>>>(e, esq);
    argmin_kernel<<<NPIX / PXB, 512, 0, stream>>>(x, e, esq, idx, out);
    gather_kernel<<<4096, 256, 0, stream>>>(x, e, idx, out, partial);
    loss_kernel<<<1, 256, 0, stream>>>(partial, out);
}